// Round 2
// baseline (279.442 us; speedup 1.0000x reference)
//
#include <hip/hip_runtime.h>
#include <hip/hip_bf16.h>

// LambdaLayer: b=4, hh=ww=16 (m=256 spatial), cin=1024, heads=4,
// dim_k=dim_v=256, dim_u=1, rel_len=31.  All inputs/outputs are FLOAT32.
//
// f32 scratch in d_ws:
//   qbn [b][sp][1024]   (after BN)         1M f32
//   ksm [b][sp][256]    (after softmax)    256K f32
//   vbn [b][sp][256]    (after BN)         256K f32
//   Lc  [b][s1][s2]                        256K f32
//   Yacc[b][n][h][v]    (content path)     1M f32
// Output: out[b][n][h*256+v] f32.

__device__ __forceinline__ void mm_tile16(const float (*As)[68], const float (*Bs)[68],
                                          float c[4][4], int tx, int ty) {
#pragma unroll
    for (int kk = 0; kk < 16; ++kk) {
        const float4 av = *reinterpret_cast<const float4*>(&As[kk][ty * 4]);
        const float4 bv = *reinterpret_cast<const float4*>(&Bs[kk][tx * 4]);
        const float a[4] = {av.x, av.y, av.z, av.w};
        const float bb[4] = {bv.x, bv.y, bv.z, bv.w};
#pragma unroll
        for (int i = 0; i < 4; ++i)
#pragma unroll
            for (int j = 0; j < 4; ++j)
                c[i][j] = fmaf(a[i], bb[j], c[i][j]);
    }
}

// ---------------- projection GEMM: C = epilogue(X @ W) ----------------
// X: 1024x1024 f32 row-major (rows = b*spatial), W: 1024xN f32, C: 1024xN f32
// EPI: 0 = raw, 1 = batchnorm over columns (eps = 1e-3)
template <int EPI>
__global__ __launch_bounds__(256) void proj_gemm(
    const float* __restrict__ X, const float* __restrict__ W,
    const float* __restrict__ gam, const float* __restrict__ bet,
    const float* __restrict__ mu, const float* __restrict__ var,
    float* __restrict__ Cout, int N) {
    const int tid = threadIdx.x;
    const int tx = tid & 15, ty = tid >> 4;
    const int m0 = blockIdx.y * 64, n0 = blockIdx.x * 64;
    __shared__ float As[16][68];
    __shared__ float Bs[16][68];
    float c[4][4] = {};

    const int arow = tid >> 2, akg = (tid & 3) * 4;  // A stage: 64 rows x 16 k
    const int bkk = tid >> 4, bcg = (tid & 15) * 4;  // B stage: 16 k x 64 cols

    for (int k0 = 0; k0 < 1024; k0 += 16) {
        const float4 fa =
            *reinterpret_cast<const float4*>(&X[(m0 + arow) * 1024 + k0 + akg]);
        As[akg + 0][arow] = fa.x;
        As[akg + 1][arow] = fa.y;
        As[akg + 2][arow] = fa.z;
        As[akg + 3][arow] = fa.w;
        const float4 fb =
            *reinterpret_cast<const float4*>(&W[(k0 + bkk) * N + n0 + bcg]);
        *reinterpret_cast<float4*>(&Bs[bkk][bcg]) = fb;
        __syncthreads();
        mm_tile16(As, Bs, c, tx, ty);
        __syncthreads();
    }
#pragma unroll
    for (int j = 0; j < 4; ++j) {
        const int col = n0 + tx * 4 + j;
        float scale = 1.f, shift = 0.f;
        if (EPI == 1) {
            const float g = gam[col], be_ = bet[col];
            const float m_ = mu[col], v_ = var[col];
            scale = g * rsqrtf(v_ + 1e-3f);
            shift = be_ - m_ * scale;
        }
#pragma unroll
        for (int i = 0; i < 4; ++i) {
            const int row = m0 + ty * 4 + i;
            Cout[row * N + col] = c[i][j] * scale + shift;
        }
    }
}

// ---------------- row softmax over 256 channels, in place ----------------
__global__ __launch_bounds__(256) void softmax_rows(float* __restrict__ KS) {
    const int row = blockIdx.x, t = threadIdx.x;
    const float v = KS[row * 256 + t];
    float m = v;
#pragma unroll
    for (int off = 1; off < 64; off <<= 1) m = fmaxf(m, __shfl_xor(m, off));
    __shared__ float wred[4];
    __shared__ float wsum[4];
    const int wid = t >> 6;
    if ((t & 63) == 0) wred[wid] = m;
    __syncthreads();
    m = fmaxf(fmaxf(wred[0], wred[1]), fmaxf(wred[2], wred[3]));
    const float e = expf(v - m);
    float s = e;
#pragma unroll
    for (int off = 1; off < 64; off <<= 1) s += __shfl_xor(s, off);
    if ((t & 63) == 0) wsum[wid] = s;
    __syncthreads();
    s = wsum[0] + wsum[1] + wsum[2] + wsum[3];
    KS[row * 256 + t] = e / s;
}

// ---------------- Lc[b] = ksm[b] @ vbn[b]^T (256x256x256 per batch) -------
__global__ __launch_bounds__(256) void lc_gemm(const float* __restrict__ Ksm,
                                               const float* __restrict__ Vbn,
                                               float* __restrict__ Lc) {
    const int tid = threadIdx.x;
    const int tx = tid & 15, ty = tid >> 4;
    const int b = blockIdx.z;
    const int m0 = blockIdx.y * 64, n0 = blockIdx.x * 64;
    const float* A = Ksm + b * 65536;
    const float* Bv = Vbn + b * 65536;
    __shared__ float As[16][68];
    __shared__ float Bs[16][68];
    float c[4][4] = {};
    const int r = tid >> 2, kg = (tid & 3) * 4;
    for (int k0 = 0; k0 < 256; k0 += 16) {
        const float4 fa = *reinterpret_cast<const float4*>(&A[(m0 + r) * 256 + k0 + kg]);
        As[kg + 0][r] = fa.x;
        As[kg + 1][r] = fa.y;
        As[kg + 2][r] = fa.z;
        As[kg + 3][r] = fa.w;
        const float4 fb = *reinterpret_cast<const float4*>(&Bv[(n0 + r) * 256 + k0 + kg]);
        Bs[kg + 0][r] = fb.x;
        Bs[kg + 1][r] = fb.y;
        Bs[kg + 2][r] = fb.z;
        Bs[kg + 3][r] = fb.w;
        __syncthreads();
        mm_tile16(As, Bs, c, tx, ty);
        __syncthreads();
    }
#pragma unroll
    for (int i = 0; i < 4; ++i)
#pragma unroll
        for (int j = 0; j < 4; ++j)
            Lc[b * 65536 + (m0 + ty * 4 + i) * 256 + n0 + tx * 4 + j] = c[i][j];
}

// -------- Yc[b,n,h,v] = sum_k q[b,h,k,n] * Lc[b,k,v], q remapped from qbn ---
__global__ __launch_bounds__(256) void yc_gemm(const float* __restrict__ Qbn,
                                               const float* __restrict__ Lc,
                                               float* __restrict__ Yacc) {
    const int tid = threadIdx.x;
    const int tx = tid & 15, ty = tid >> 4;
    const int bh = blockIdx.z, b = bh >> 2, h = bh & 3;
    const int n0 = blockIdx.y * 64, v0 = blockIdx.x * 64;
    __shared__ float As[16][68];
    __shared__ float Bs[16][68];
    float c[4][4] = {};
    const int skk = tid >> 4, sg = (tid & 15) * 4;
    for (int k0 = 0; k0 < 256; k0 += 16) {
        const int k = k0 + skk;
        // A[n][k] = qbn[b][h*64 + k/4][(k&3)*256 + n]  (contiguous in n)
        const float4 fa = *reinterpret_cast<const float4*>(
            &Qbn[(b * 256 + h * 64 + (k >> 2)) * 1024 + (k & 3) * 256 + n0 + sg]);
        *reinterpret_cast<float4*>(&As[skk][sg]) = fa;
        const float4 fb =
            *reinterpret_cast<const float4*>(&Lc[(b * 256 + k) * 256 + v0 + sg]);
        *reinterpret_cast<float4*>(&Bs[skk][sg]) = fb;
        __syncthreads();
        mm_tile16(As, Bs, c, tx, ty);
        __syncthreads();
    }
#pragma unroll
    for (int i = 0; i < 4; ++i)
#pragma unroll
        for (int j = 0; j < 4; ++j)
            Yacc[((b * 256 + n0 + ty * 4 + i) * 4 + h) * 256 + v0 + tx * 4 + j] =
                c[i][j];
}

// ------- fused position path, one block per (b, n) ------------------------
// S[h][m] = sum_k q[b,h,k,n] * rpe[ridx(n,m)][k]
// Yp[h][v] = sum_m S[h][m] * vbn[b][v][m];  out = Yp + Yacc
__global__ __launch_bounds__(256) void syp_kernel(
    const float* __restrict__ Qbn, const float* __restrict__ Rpe,
    const float* __restrict__ Vbn, const float* __restrict__ Yacc,
    float* __restrict__ Out) {
    const int n = blockIdx.x, b = blockIdx.y;
    const int t = threadIdx.x;
    __shared__ float Qs[4][256];
    __shared__ float Ss[4][256];
#pragma unroll
    for (int h = 0; h < 4; ++h)
        Qs[h][t] = Qbn[(b * 256 + h * 64 + (t >> 2)) * 1024 + (t & 3) * 256 + n];
    __syncthreads();

    const int in_ = n >> 4, jn = n & 15;
    const int im = t >> 4, jm = t & 15;
    const int ridx = (im - in_ + 15) * 31 + (jm - jn + 15);
    const float4* r4 = reinterpret_cast<const float4*>(Rpe + ridx * 256);
    float s0 = 0.f, s1 = 0.f, s2 = 0.f, s3 = 0.f;
#pragma unroll 4
    for (int k4 = 0; k4 < 64; ++k4) {
        const float4 u = r4[k4];
        const int k = k4 * 4;
        s0 += Qs[0][k] * u.x + Qs[0][k + 1] * u.y + Qs[0][k + 2] * u.z + Qs[0][k + 3] * u.w;
        s1 += Qs[1][k] * u.x + Qs[1][k + 1] * u.y + Qs[1][k + 2] * u.z + Qs[1][k + 3] * u.w;
        s2 += Qs[2][k] * u.x + Qs[2][k + 1] * u.y + Qs[2][k + 2] * u.z + Qs[2][k + 3] * u.w;
        s3 += Qs[3][k] * u.x + Qs[3][k + 1] * u.y + Qs[3][k + 2] * u.z + Qs[3][k + 3] * u.w;
    }
    Ss[0][t] = s0;
    Ss[1][t] = s1;
    Ss[2][t] = s2;
    Ss[3][t] = s3;
    __syncthreads();

    const float4* v4 = reinterpret_cast<const float4*>(Vbn + (b * 256 + t) * 256);
    float y0 = 0.f, y1 = 0.f, y2 = 0.f, y3 = 0.f;
#pragma unroll 4
    for (int m4 = 0; m4 < 64; ++m4) {
        const float4 vm = v4[m4];
        const int m = m4 * 4;
        y0 += Ss[0][m] * vm.x + Ss[0][m + 1] * vm.y + Ss[0][m + 2] * vm.z + Ss[0][m + 3] * vm.w;
        y1 += Ss[1][m] * vm.x + Ss[1][m + 1] * vm.y + Ss[1][m + 2] * vm.z + Ss[1][m + 3] * vm.w;
        y2 += Ss[2][m] * vm.x + Ss[2][m + 1] * vm.y + Ss[2][m + 2] * vm.z + Ss[2][m + 3] * vm.w;
        y3 += Ss[3][m] * vm.x + Ss[3][m + 1] * vm.y + Ss[3][m + 2] * vm.z + Ss[3][m + 3] * vm.w;
    }
    const int base = (b * 256 + n) * 1024 + t;
    Out[base + 0 * 256] = y0 + Yacc[base + 0 * 256];
    Out[base + 1 * 256] = y1 + Yacc[base + 1 * 256];
    Out[base + 2 * 256] = y2 + Yacc[base + 2 * 256];
    Out[base + 3 * 256] = y3 + Yacc[base + 3 * 256];
}

extern "C" void kernel_launch(void* const* d_in, const int* in_sizes, int n_in,
                              void* d_out, int out_size, void* d_ws, size_t ws_size,
                              hipStream_t stream) {
    const float* x = (const float*)d_in[0];
    const float* Wq = (const float*)d_in[1];
    const float* Wk = (const float*)d_in[2];
    const float* Wv = (const float*)d_in[3];
    const float* qg = (const float*)d_in[4];
    const float* qb = (const float*)d_in[5];
    const float* qm = (const float*)d_in[6];
    const float* qv = (const float*)d_in[7];
    const float* vg = (const float*)d_in[8];
    const float* vb = (const float*)d_in[9];
    const float* vm = (const float*)d_in[10];
    const float* vvar = (const float*)d_in[11];
    const float* rpe = (const float*)d_in[12];
    float* out = (float*)d_out;

    float* qbn = (float*)d_ws;          // 1048576 f32
    float* ksm = qbn + 1048576;         // 262144
    float* vbn = ksm + 262144;          // 262144
    float* Lc = vbn + 262144;           // 262144
    float* Yacc = Lc + 262144;          // 1048576   (total ~11.5 MB)

    const dim3 blk(256);
    proj_gemm<1><<<dim3(16, 16), blk, 0, stream>>>(x, Wq, qg, qb, qm, qv, qbn, 1024);
    proj_gemm<0><<<dim3(4, 16), blk, 0, stream>>>(x, Wk, nullptr, nullptr, nullptr,
                                                  nullptr, ksm, 256);
    proj_gemm<1><<<dim3(4, 16), blk, 0, stream>>>(x, Wv, vg, vb, vm, vvar, vbn, 256);
    softmax_rows<<<1024, blk, 0, stream>>>(ksm);
    lc_gemm<<<dim3(4, 4, 4), blk, 0, stream>>>(ksm, vbn, Lc);
    yc_gemm<<<dim3(4, 4, 16), blk, 0, stream>>>(qbn, Lc, Yacc);
    syp_kernel<<<dim3(256, 4), blk, 0, stream>>>(qbn, rpe, vbn, Yacc, out);
}

// Round 3
// 70.176 us; speedup vs baseline: 3.9820x; 3.9820x over previous
//
#include <hip/hip_runtime.h>

// LambdaLayer b=4, m=256 spatial, cin=1024, heads=4, dim_k=dim_v=256, u=1.
// All device inputs/outputs are f32; compute in bf16 MFMA with f32 accum.
//
// ws layout (11 MB total, == round-2 usage):
//  0x000000 xb   [1024][1024] bf16   x cast
//  0x200000 WqT  [1024][1024] bf16   Wq^T (dout, c)
//  0x400000 WkT  [256][1024]  bf16
//  0x480000 WvT  [256][1024]  bf16
//  0x500000 rpeb [961][256]   bf16   rel_pos_emb cast
//  0x580000 Q2   [16bh][256n][256kk] bf16  q remapped: Q2[bh][n][kk]=qbn[s][d]
//  0x780000 ksm  [1024][256]  bf16   softmax(k)
//  0x800000 vbn  [1024][256]  bf16   BN(v)
//  0x880000 LcT  [4][256v][256kk] bf16
//  0x900000 S    [256n][16bh][256m] bf16   (first 1MB aliases kn f32 earlier)

typedef __bf16 bf16;
typedef __attribute__((ext_vector_type(8))) __bf16 bf16x8;
typedef __attribute__((ext_vector_type(4))) float f32x4;

__device__ __forceinline__ bf16x8 ld8(const bf16* p) {
    return *reinterpret_cast<const bf16x8*>(p);
}

// ---------------- prep: casts + weight transposes -------------------------
__global__ __launch_bounds__(256) void prep(
    const float* __restrict__ x, const float* __restrict__ Wq,
    const float* __restrict__ Wk, const float* __restrict__ Wv,
    const float* __restrict__ rpe, bf16* __restrict__ xb,
    bf16* __restrict__ WqT, bf16* __restrict__ WkT, bf16* __restrict__ WvT,
    bf16* __restrict__ rpeb) {
    __shared__ float tile[32][33];
    const int bid = blockIdx.x, tid = threadIdx.x;
    const float* W = nullptr;
    bf16* WT = nullptr;
    int ldw = 0, ci = 0, di = 0;
    if (bid < 1024) {
        W = Wq; WT = WqT; ldw = 1024; ci = bid >> 5; di = bid & 31;
    } else if (bid < 1280) {
        const int t2 = bid - 1024;
        W = Wk; WT = WkT; ldw = 256; ci = t2 >> 3; di = t2 & 7;
    } else if (bid < 1536) {
        const int t2 = bid - 1280;
        W = Wv; WT = WvT; ldw = 256; ci = t2 >> 3; di = t2 & 7;
    }
    if (W) {  // transpose-cast one 32x32 tile: WT[d][c] = W[c][d]
        const int r = tid >> 3, c4 = (tid & 7) * 4;
        const float4 v =
            *reinterpret_cast<const float4*>(&W[(ci * 32 + r) * ldw + di * 32 + c4]);
        tile[r][c4 + 0] = v.x;
        tile[r][c4 + 1] = v.y;
        tile[r][c4 + 2] = v.z;
        tile[r][c4 + 3] = v.w;
        __syncthreads();
        bf16* dst = &WT[(di * 32 + r) * 1024 + ci * 32 + c4];
        dst[0] = (bf16)tile[c4 + 0][r];
        dst[1] = (bf16)tile[c4 + 1][r];
        dst[2] = (bf16)tile[c4 + 2][r];
        dst[3] = (bf16)tile[c4 + 3][r];
        return;
    }
    if (bid < 1792) {  // xb cast: 256 blocks x 1024 float4
        const int base = (bid - 1536) * 1024 + tid;
        const float4* xs = reinterpret_cast<const float4*>(x);
#pragma unroll
        for (int j = 0; j < 4; ++j) {
            const float4 v = xs[base + j * 256];
            bf16* d = &xb[(base + j * 256) * 4];
            d[0] = (bf16)v.x; d[1] = (bf16)v.y; d[2] = (bf16)v.z; d[3] = (bf16)v.w;
        }
        return;
    }
    {  // rpeb cast: 61504 float4 units
        const int base = (bid - 1792) * 1024 + tid;
        const float4* rs = reinterpret_cast<const float4*>(rpe);
#pragma unroll
        for (int j = 0; j < 4; ++j) {
            const int idx = base + j * 256;
            if (idx < 61504) {
                const float4 v = rs[idx];
                bf16* d = &rpeb[idx * 4];
                d[0] = (bf16)v.x; d[1] = (bf16)v.y; d[2] = (bf16)v.z; d[3] = (bf16)v.w;
            }
        }
    }
}

// ------------- shared MFMA K-pass: 64x64 tile, BK=64, 4 waves --------------
template <int PA, int PB>
__device__ __forceinline__ void kpass(const bf16* __restrict__ Ap, int offA,
                                      const bf16* __restrict__ Bp,
                                      bf16* __restrict__ Al, bf16* __restrict__ Bl,
                                      f32x4 (&acc)[2][2], int m0, int n0,
                                      int nsteps) {
    const int tid = threadIdx.x;
    const int w = tid >> 6, l = tid & 63;
    const int sr0 = tid >> 3, sc = (tid & 7) * 8;
    const int wr = (w >> 1) * 32, wc = (w & 1) * 32;
    const int fr = l & 15, fk = (l >> 4) * 8;
    const bf16* arow0 = Ap + (m0 + sr0) * PA + offA + sc;
    const bf16* arow1 = Ap + (m0 + 32 + sr0) * PA + offA + sc;
    const bf16* brow0 = Bp + (n0 + sr0) * PB + sc;
    const bf16* brow1 = Bp + (n0 + 32 + sr0) * PB + sc;
    bf16x8 a0 = ld8(arow0), a1 = ld8(arow1), b0 = ld8(brow0), b1 = ld8(brow1);
    for (int kt = 0; kt < nsteps; ++kt) {
        __syncthreads();  // previous tile's reads complete
        *reinterpret_cast<bf16x8*>(&Al[tid * 8]) = a0;
        *reinterpret_cast<bf16x8*>(&Al[2048 + tid * 8]) = a1;
        *reinterpret_cast<bf16x8*>(&Bl[tid * 8]) = b0;
        *reinterpret_cast<bf16x8*>(&Bl[2048 + tid * 8]) = b1;
        __syncthreads();
        if (kt + 1 < nsteps) {  // prefetch next tile during compute
            const int k0 = (kt + 1) * 64;
            a0 = ld8(arow0 + k0);
            a1 = ld8(arow1 + k0);
            b0 = ld8(brow0 + k0);
            b1 = ld8(brow1 + k0);
        }
#pragma unroll
        for (int ks = 0; ks < 2; ++ks) {
            const bf16x8 af0 = ld8(&Al[(wr + fr) * 64 + ks * 32 + fk]);
            const bf16x8 af1 = ld8(&Al[(wr + 16 + fr) * 64 + ks * 32 + fk]);
            const bf16x8 bg0 = ld8(&Bl[(wc + fr) * 64 + ks * 32 + fk]);
            const bf16x8 bg1 = ld8(&Bl[(wc + 16 + fr) * 64 + ks * 32 + fk]);
            acc[0][0] = __builtin_amdgcn_mfma_f32_16x16x32_bf16(af0, bg0, acc[0][0], 0, 0, 0);
            acc[0][1] = __builtin_amdgcn_mfma_f32_16x16x32_bf16(af0, bg1, acc[0][1], 0, 0, 0);
            acc[1][0] = __builtin_amdgcn_mfma_f32_16x16x32_bf16(af1, bg0, acc[1][0], 0, 0, 0);
            acc[1][1] = __builtin_amdgcn_mfma_f32_16x16x32_bf16(af1, bg1, acc[1][1], 0, 0, 0);
        }
    }
}

// MODE 0: q proj (K=1024, BN, scatter to Q2 bf16)
// MODE 1: k proj (K=1024, raw f32 out)
// MODE 2: v proj (K=1024, BN, bf16 natural out)
// MODE 3: LcT[b][v][kk] = sum_d vbn[v][d]*ksm[kk][d]  (K=256, bf16 out)
// MODE 4: out = Q2*LcT^T + S*vbn^T  (K=256+256, f32 out)
template <int MODE>
__global__ __launch_bounds__(256) void gk(
    const bf16* __restrict__ Ag, const bf16* __restrict__ Bg,
    const float* __restrict__ gam, const float* __restrict__ bet,
    const float* __restrict__ mu, const float* __restrict__ var,
    void* __restrict__ outp, const bf16* __restrict__ A1,
    const bf16* __restrict__ B1) {
    constexpr int LDA = (MODE <= 2) ? 1024 : 256;
    constexpr int LDB = (MODE <= 2) ? 1024 : 256;
    constexpr int KSTEPS = (MODE <= 2) ? 16 : 4;
    const int tid = threadIdx.x;
    const int w = tid >> 6, l = tid & 63;
    const int m0 = blockIdx.y * 64, n0 = blockIdx.x * 64;
    const int z = blockIdx.z;
    __shared__ __align__(16) bf16 Al[4096];
    __shared__ __align__(16) bf16 Bl[4096];

    const bf16* Ap = Ag + ((MODE >= 3) ? z * 65536 : 0);
    const bf16* Bp = Bg + ((MODE == 3) ? z * 65536 : ((MODE == 4) ? (z >> 2) * 65536 : 0));

    f32x4 acc[2][2] = {};
    kpass<LDA, LDB>(Ap, 0, Bp, Al, Bl, acc, m0, n0, KSTEPS);
    if constexpr (MODE == 4) {  // position-path pass: A = S[n][bh][m], B = vbn
        kpass<4096, 256>(A1, z * 256, B1 + (z >> 2) * 65536, Al, Bl, acc, m0, n0, 4);
    }

    const int wr = (w >> 1) * 32, wc = (w & 1) * 32;
    const int drow = (l >> 4) * 4, dcol = l & 15;
#pragma unroll
    for (int ms = 0; ms < 2; ++ms) {
#pragma unroll
        for (int ns = 0; ns < 2; ++ns) {
            const int gc = n0 + wc + ns * 16 + dcol;
            float scale = 1.f, shift = 0.f;
            if constexpr (MODE == 0 || MODE == 2) {
                scale = gam[gc] * rsqrtf(var[gc] + 1e-3f);
                shift = bet[gc] - mu[gc] * scale;
            }
#pragma unroll
            for (int r = 0; r < 4; ++r) {
                const int gr = m0 + wr + ms * 16 + drow + r;
                const float val = acc[ms][ns][r] * scale + shift;
                if constexpr (MODE == 0) {
                    // q remap: s=gr, d=gc -> Q2[s>>6][d&255][(s&63)*4+(d>>8)]
                    bf16* Q2 = (bf16*)outp;
                    const int bh = gr >> 6;
                    const int kk = (gr & 63) * 4 + (gc >> 8);
                    const int n = gc & 255;
                    Q2[bh * 65536 + n * 256 + kk] = (bf16)val;
                } else if constexpr (MODE == 1) {
                    ((float*)outp)[gr * 256 + gc] = val;
                } else if constexpr (MODE == 2) {
                    ((bf16*)outp)[gr * 256 + gc] = (bf16)val;
                } else if constexpr (MODE == 3) {
                    ((bf16*)outp)[z * 65536 + gr * 256 + gc] = (bf16)val;
                } else {
                    ((float*)outp)[(z >> 2) * 262144 + gr * 1024 + (z & 3) * 256 + gc] = val;
                }
            }
        }
    }
}

// ---------------- row softmax over channels: kn f32 -> ksm bf16 ------------
__global__ __launch_bounds__(256) void softmax_rows(const float* __restrict__ KN,
                                                    bf16* __restrict__ KSM) {
    const int row = blockIdx.x, t = threadIdx.x;
    const float v = KN[row * 256 + t];
    float m = v;
#pragma unroll
    for (int off = 1; off < 64; off <<= 1) m = fmaxf(m, __shfl_xor(m, off));
    __shared__ float wred[4], wsum[4];
    const int wid = t >> 6;
    if ((t & 63) == 0) wred[wid] = m;
    __syncthreads();
    m = fmaxf(fmaxf(wred[0], wred[1]), fmaxf(wred[2], wred[3]));
    const float e = expf(v - m);
    float s = e;
#pragma unroll
    for (int off = 1; off < 64; off <<= 1) s += __shfl_xor(s, off);
    if ((t & 63) == 0) wsum[wid] = s;
    __syncthreads();
    s = wsum[0] + wsum[1] + wsum[2] + wsum[3];
    KSM[row * 256 + t] = (bf16)(e / s);
}

// ------- S[n][bh][m] = sum_k rel[n][m][k] * Q2[bh][n][k] -------------------
__global__ __launch_bounds__(256) void s_gemm(const bf16* __restrict__ rpeb,
                                              const bf16* __restrict__ Q2,
                                              bf16* __restrict__ S) {
    const int tid = threadIdx.x;
    const int w = tid >> 6, l = tid & 63;
    const int m0 = blockIdx.x * 64;
    const int n = blockIdx.y;
    const int in_ = n >> 4, jn = n & 15;
    __shared__ __align__(16) bf16 Al[64 * 256];  // 32 KB: rel rows
    __shared__ __align__(16) bf16 Bl[16 * 256];  // 8 KB: Q2[.][n][.]
#pragma unroll
    for (int i = 0; i < 2; ++i) {
        const int slot = tid + i * 256;
        const int row = slot >> 5, k8 = (slot & 31) * 8;
        *reinterpret_cast<bf16x8*>(&Bl[slot * 8]) = ld8(Q2 + row * 65536 + n * 256 + k8);
    }
#pragma unroll
    for (int i = 0; i < 8; ++i) {
        const int slot = tid + i * 256;
        const int row = slot >> 5, k8 = (slot & 31) * 8;
        const int m = m0 + row;
        const int ridx = ((m >> 4) - in_ + 15) * 31 + ((m & 15) - jn + 15);
        *reinterpret_cast<bf16x8*>(&Al[slot * 8]) = ld8(rpeb + ridx * 256 + k8);
    }
    __syncthreads();
    const int fr = l & 15, fk = (l >> 4) * 8;
    f32x4 acc = {};
#pragma unroll
    for (int ks = 0; ks < 8; ++ks) {
        const bf16x8 af = ld8(&Al[(w * 16 + fr) * 256 + ks * 32 + fk]);
        const bf16x8 bg = ld8(&Bl[fr * 256 + ks * 32 + fk]);
        acc = __builtin_amdgcn_mfma_f32_16x16x32_bf16(af, bg, acc, 0, 0, 0);
    }
    const int drow = (l >> 4) * 4, bh = l & 15;
#pragma unroll
    for (int r = 0; r < 4; ++r) {
        const int m = m0 + w * 16 + drow + r;
        S[n * 4096 + bh * 256 + m] = (bf16)acc[r];
    }
}

extern "C" void kernel_launch(void* const* d_in, const int* in_sizes, int n_in,
                              void* d_out, int out_size, void* d_ws, size_t ws_size,
                              hipStream_t stream) {
    const float* x = (const float*)d_in[0];
    const float* Wq = (const float*)d_in[1];
    const float* Wk = (const float*)d_in[2];
    const float* Wv = (const float*)d_in[3];
    const float* qg = (const float*)d_in[4];
    const float* qb = (const float*)d_in[5];
    const float* qm = (const float*)d_in[6];
    const float* qv = (const float*)d_in[7];
    const float* vg = (const float*)d_in[8];
    const float* vb = (const float*)d_in[9];
    const float* vm = (const float*)d_in[10];
    const float* vvar = (const float*)d_in[11];
    const float* rpe = (const float*)d_in[12];
    float* out = (float*)d_out;

    char* wsb = (char*)d_ws;
    bf16* xb = (bf16*)(wsb);
    bf16* WqT = (bf16*)(wsb + 0x200000u);
    bf16* WkT = (bf16*)(wsb + 0x400000u);
    bf16* WvT = (bf16*)(wsb + 0x480000u);
    bf16* rpeb = (bf16*)(wsb + 0x500000u);
    bf16* Q2 = (bf16*)(wsb + 0x580000u);
    bf16* ksm = (bf16*)(wsb + 0x780000u);
    bf16* vbn = (bf16*)(wsb + 0x800000u);
    bf16* LcT = (bf16*)(wsb + 0x880000u);
    bf16* S = (bf16*)(wsb + 0x900000u);
    float* kn = (float*)(wsb + 0x900000u);  // aliases S; consumed before S written

    const dim3 blk(256);
    prep<<<1853, blk, 0, stream>>>(x, Wq, Wk, Wv, rpe, xb, WqT, WkT, WvT, rpeb);
    gk<0><<<dim3(16, 16), blk, 0, stream>>>(xb, WqT, qg, qb, qm, qv, Q2, nullptr, nullptr);
    gk<1><<<dim3(4, 16), blk, 0, stream>>>(xb, WkT, nullptr, nullptr, nullptr, nullptr,
                                           kn, nullptr, nullptr);
    gk<2><<<dim3(4, 16), blk, 0, stream>>>(xb, WvT, vg, vb, vm, vvar, vbn, nullptr, nullptr);
    softmax_rows<<<1024, blk, 0, stream>>>(kn, ksm);
    gk<3><<<dim3(4, 4, 4), blk, 0, stream>>>(vbn, ksm, nullptr, nullptr, nullptr, nullptr,
                                             LcT, nullptr, nullptr);
    s_gemm<<<dim3(4, 256), blk, 0, stream>>>(rpeb, Q2, S);
    gk<4><<<dim3(4, 4, 16), blk, 0, stream>>>(Q2, LcT, nullptr, nullptr, nullptr, nullptr,
                                              out, S, vbn);
}

// Round 4
// 42.860 us; speedup vs baseline: 6.5198x; 1.6373x over previous
//
#include <hip/hip_runtime.h>

// LambdaLayer b=4, m=256 spatial, cin=1024, heads=4, dim_k=dim_v=256, u=1.
// f32 in/out; bf16 MFMA compute with f32 accum. LDS tiles XOR-swizzled
// (elem ^= (row&7)<<3, i.e. 16B-granule XOR) to kill 16-way bank conflicts.

typedef __bf16 bf16;
typedef __attribute__((ext_vector_type(8))) __bf16 bf16x8;
typedef __attribute__((ext_vector_type(4))) float f32x4;

__device__ __forceinline__ bf16x8 ld8(const bf16* p) {
    return *reinterpret_cast<const bf16x8*>(p);
}

// ---------------- prep: casts + weight transposes -------------------------
__global__ __launch_bounds__(256) void prep(
    const float* __restrict__ x, const float* __restrict__ Wq,
    const float* __restrict__ Wk, const float* __restrict__ Wv,
    const float* __restrict__ rpe, bf16* __restrict__ xb,
    bf16* __restrict__ WqT, bf16* __restrict__ WkT, bf16* __restrict__ WvT,
    bf16* __restrict__ rpeb) {
    __shared__ float tile[32][33];
    const int bid = blockIdx.x, tid = threadIdx.x;
    const float* W = nullptr;
    bf16* WT = nullptr;
    int ldw = 0, ci = 0, di = 0;
    if (bid < 1024) {
        W = Wq; WT = WqT; ldw = 1024; ci = bid >> 5; di = bid & 31;
    } else if (bid < 1280) {
        const int t2 = bid - 1024;
        W = Wk; WT = WkT; ldw = 256; ci = t2 >> 3; di = t2 & 7;
    } else if (bid < 1536) {
        const int t2 = bid - 1280;
        W = Wv; WT = WvT; ldw = 256; ci = t2 >> 3; di = t2 & 7;
    }
    if (W) {  // transpose-cast one 32x32 tile: WT[d][c] = W[c][d]
        const int r = tid >> 3, c4 = (tid & 7) * 4;
        const float4 v =
            *reinterpret_cast<const float4*>(&W[(ci * 32 + r) * ldw + di * 32 + c4]);
        tile[r][c4 + 0] = v.x;
        tile[r][c4 + 1] = v.y;
        tile[r][c4 + 2] = v.z;
        tile[r][c4 + 3] = v.w;
        __syncthreads();
        bf16* dst = &WT[(di * 32 + r) * 1024 + ci * 32 + c4];
        dst[0] = (bf16)tile[c4 + 0][r];
        dst[1] = (bf16)tile[c4 + 1][r];
        dst[2] = (bf16)tile[c4 + 2][r];
        dst[3] = (bf16)tile[c4 + 3][r];
        return;
    }
    if (bid < 1792) {  // xb cast
        const int base = (bid - 1536) * 1024 + tid;
        const float4* xs = reinterpret_cast<const float4*>(x);
#pragma unroll
        for (int j = 0; j < 4; ++j) {
            const float4 v = xs[base + j * 256];
            bf16* d = &xb[(base + j * 256) * 4];
            d[0] = (bf16)v.x; d[1] = (bf16)v.y; d[2] = (bf16)v.z; d[3] = (bf16)v.w;
        }
        return;
    }
    {  // rpeb cast
        const int base = (bid - 1792) * 1024 + tid;
        const float4* rs = reinterpret_cast<const float4*>(rpe);
#pragma unroll
        for (int j = 0; j < 4; ++j) {
            const int idx = base + j * 256;
            if (idx < 61504) {
                const float4 v = rs[idx];
                bf16* d = &rpeb[idx * 4];
                d[0] = (bf16)v.x; d[1] = (bf16)v.y; d[2] = (bf16)v.z; d[3] = (bf16)v.w;
            }
        }
    }
}

// ------------- shared MFMA K-pass: 64x64 tile, BK=64, 4 waves --------------
// LDS tiles are [64 rows][64 bf16], 16B granules XOR-swizzled by (row&7).
template <int PA, int PB>
__device__ __forceinline__ void kpass(const bf16* __restrict__ Ap, int offA,
                                      const bf16* __restrict__ Bp,
                                      bf16* __restrict__ Al, bf16* __restrict__ Bl,
                                      f32x4 (&acc)[2][2], int m0, int n0,
                                      int nsteps) {
    const int tid = threadIdx.x;
    const int w = tid >> 6, l = tid & 63;
    const int sr0 = tid >> 3, sg = tid & 7;
    const int wr = (w >> 1) * 32, wc = (w & 1) * 32;
    const int fr = l & 15, fk = (l >> 4) * 8;
    const int st0 = sr0 * 64 + ((sg ^ (sr0 & 7)) << 3);         // rows 0..31
    const int st1 = (sr0 + 32) * 64 + ((sg ^ (sr0 & 7)) << 3);  // rows 32..63
    const int fx = (fr & 7) << 3;  // read-side XOR (same for row, row+16, row+32)
    const bf16* arow0 = Ap + (m0 + sr0) * PA + offA + sg * 8;
    const bf16* arow1 = Ap + (m0 + 32 + sr0) * PA + offA + sg * 8;
    const bf16* brow0 = Bp + (n0 + sr0) * PB + sg * 8;
    const bf16* brow1 = Bp + (n0 + 32 + sr0) * PB + sg * 8;
    bf16x8 a0 = ld8(arow0), a1 = ld8(arow1), b0 = ld8(brow0), b1 = ld8(brow1);
    for (int kt = 0; kt < nsteps; ++kt) {
        __syncthreads();  // previous tile's reads complete
        *reinterpret_cast<bf16x8*>(&Al[st0]) = a0;
        *reinterpret_cast<bf16x8*>(&Al[st1]) = a1;
        *reinterpret_cast<bf16x8*>(&Bl[st0]) = b0;
        *reinterpret_cast<bf16x8*>(&Bl[st1]) = b1;
        __syncthreads();
        if (kt + 1 < nsteps) {  // prefetch next tile during compute
            const int k0 = (kt + 1) * 64;
            a0 = ld8(arow0 + k0);
            a1 = ld8(arow1 + k0);
            b0 = ld8(brow0 + k0);
            b1 = ld8(brow1 + k0);
        }
#pragma unroll
        for (int ks = 0; ks < 2; ++ks) {
            const int eo = (ks * 32 + fk) ^ fx;
            const bf16x8 af0 = ld8(&Al[(wr + fr) * 64 + eo]);
            const bf16x8 af1 = ld8(&Al[(wr + 16 + fr) * 64 + eo]);
            const bf16x8 bg0 = ld8(&Bl[(wc + fr) * 64 + eo]);
            const bf16x8 bg1 = ld8(&Bl[(wc + 16 + fr) * 64 + eo]);
            acc[0][0] = __builtin_amdgcn_mfma_f32_16x16x32_bf16(af0, bg0, acc[0][0], 0, 0, 0);
            acc[0][1] = __builtin_amdgcn_mfma_f32_16x16x32_bf16(af0, bg1, acc[0][1], 0, 0, 0);
            acc[1][0] = __builtin_amdgcn_mfma_f32_16x16x32_bf16(af1, bg0, acc[1][0], 0, 0, 0);
            acc[1][1] = __builtin_amdgcn_mfma_f32_16x16x32_bf16(af1, bg1, acc[1][1], 0, 0, 0);
        }
    }
}

// ------------- fused q/k/v projection: one launch, grid (4,16,6) -----------
// z<4: q (N-slice z*256..), BN, scatter to Q2.  z==4: k raw f32.  z==5: v BN.
__global__ __launch_bounds__(256) void proj_all(
    const bf16* __restrict__ xb, const bf16* __restrict__ WqT,
    const bf16* __restrict__ WkT, const bf16* __restrict__ WvT,
    const float* __restrict__ qg, const float* __restrict__ qb,
    const float* __restrict__ qm, const float* __restrict__ qv,
    const float* __restrict__ vg, const float* __restrict__ vb,
    const float* __restrict__ vm, const float* __restrict__ vvar,
    bf16* __restrict__ Q2, float* __restrict__ kn, bf16* __restrict__ vbn) {
    const int z = blockIdx.z;
    const int m0 = blockIdx.y * 64;
    const int tid = threadIdx.x;
    const int w = tid >> 6, l = tid & 63;
    int n0, mode;
    const bf16* Bg;
    if (z < 4) { mode = 0; Bg = WqT; n0 = (z * 4 + blockIdx.x) * 64; }
    else if (z == 4) { mode = 1; Bg = WkT; n0 = blockIdx.x * 64; }
    else { mode = 2; Bg = WvT; n0 = blockIdx.x * 64; }
    __shared__ __align__(16) bf16 Al[4096];
    __shared__ __align__(16) bf16 Bl[4096];
    f32x4 acc[2][2] = {};
    kpass<1024, 1024>(xb, 0, Bg, Al, Bl, acc, m0, n0, 16);

    const int wr = (w >> 1) * 32, wc = (w & 1) * 32;
    const int drow = (l >> 4) * 4, dcol = l & 15;
#pragma unroll
    for (int ms = 0; ms < 2; ++ms) {
#pragma unroll
        for (int ns = 0; ns < 2; ++ns) {
            const int gc = n0 + wc + ns * 16 + dcol;
            float scale = 1.f, shift = 0.f;
            if (mode == 0) {
                scale = qg[gc] * rsqrtf(qv[gc] + 1e-3f);
                shift = qb[gc] - qm[gc] * scale;
            } else if (mode == 2) {
                scale = vg[gc] * rsqrtf(vvar[gc] + 1e-3f);
                shift = vb[gc] - vm[gc] * scale;
            }
#pragma unroll
            for (int r = 0; r < 4; ++r) {
                const int gr = m0 + wr + ms * 16 + drow + r;
                const float val = acc[ms][ns][r] * scale + shift;
                if (mode == 0) {
                    const int bh = gr >> 6;
                    const int kk = (gr & 63) * 4 + (gc >> 8);
                    Q2[bh * 65536 + (gc & 255) * 256 + kk] = (bf16)val;
                } else if (mode == 1) {
                    kn[gr * 256 + gc] = val;
                } else {
                    vbn[gr * 256 + gc] = (bf16)val;
                }
            }
        }
    }
}

// MODE 3: LcT[b][v][kk] = sum_d vbn[v][d]*ksm[kk][d]  (K=256, bf16 out)
// MODE 4: out = Q2*LcT^T + S*vbn^T  (K=256+256, f32 out)
template <int MODE>
__global__ __launch_bounds__(256) void gk(
    const bf16* __restrict__ Ag, const bf16* __restrict__ Bg,
    void* __restrict__ outp, const bf16* __restrict__ A1,
    const bf16* __restrict__ B1) {
    const int tid = threadIdx.x;
    const int w = tid >> 6, l = tid & 63;
    const int m0 = blockIdx.y * 64, n0 = blockIdx.x * 64;
    const int z = blockIdx.z;
    __shared__ __align__(16) bf16 Al[4096];
    __shared__ __align__(16) bf16 Bl[4096];

    const bf16* Ap = Ag + z * 65536;
    const bf16* Bp = Bg + ((MODE == 3) ? z * 65536 : (z >> 2) * 65536);

    f32x4 acc[2][2] = {};
    kpass<256, 256>(Ap, 0, Bp, Al, Bl, acc, m0, n0, 4);
    if constexpr (MODE == 4) {  // position-path pass: A = S[n][bh][m], B = vbn
        kpass<4096, 256>(A1, z * 256, B1 + (z >> 2) * 65536, Al, Bl, acc, m0, n0, 4);
    }

    const int wr = (w >> 1) * 32, wc = (w & 1) * 32;
    const int drow = (l >> 4) * 4, dcol = l & 15;
#pragma unroll
    for (int ms = 0; ms < 2; ++ms) {
#pragma unroll
        for (int ns = 0; ns < 2; ++ns) {
            const int gc = n0 + wc + ns * 16 + dcol;
#pragma unroll
            for (int r = 0; r < 4; ++r) {
                const int gr = m0 + wr + ms * 16 + drow + r;
                if constexpr (MODE == 3) {
                    ((bf16*)outp)[z * 65536 + gr * 256 + gc] = (bf16)acc[ms][ns][r];
                } else {
                    ((float*)outp)[(z >> 2) * 262144 + gr * 1024 + (z & 3) * 256 + gc] =
                        acc[ms][ns][r];
                }
            }
        }
    }
}

// ------------- softmax over channels: wave per row, grid 256 ---------------
__global__ __launch_bounds__(256) void softmax_rows(const float* __restrict__ KN,
                                                    bf16* __restrict__ KSM) {
    const int w = threadIdx.x >> 6, l = threadIdx.x & 63;
    const int row = blockIdx.x * 4 + w;
    const float4 v = *reinterpret_cast<const float4*>(&KN[row * 256 + l * 4]);
    float m = fmaxf(fmaxf(v.x, v.y), fmaxf(v.z, v.w));
#pragma unroll
    for (int off = 1; off < 64; off <<= 1) m = fmaxf(m, __shfl_xor(m, off));
    const float e0 = expf(v.x - m), e1 = expf(v.y - m), e2 = expf(v.z - m),
                e3 = expf(v.w - m);
    float s = e0 + e1 + e2 + e3;
#pragma unroll
    for (int off = 1; off < 64; off <<= 1) s += __shfl_xor(s, off);
    const float inv = 1.f / s;
    bf16 o[4] = {(bf16)(e0 * inv), (bf16)(e1 * inv), (bf16)(e2 * inv),
                 (bf16)(e3 * inv)};
    *reinterpret_cast<uint2*>(&KSM[row * 256 + l * 4]) =
        *reinterpret_cast<uint2*>(o);
}

// ------- S[n][bh][m] = sum_k rel[n][m][k] * Q2[bh][n][k] -------------------
__global__ __launch_bounds__(256) void s_gemm(const bf16* __restrict__ rpeb,
                                              const bf16* __restrict__ Q2,
                                              bf16* __restrict__ S) {
    const int tid = threadIdx.x;
    const int w = tid >> 6, l = tid & 63;
    const int m0 = blockIdx.x * 64;
    const int n = blockIdx.y;
    const int in_ = n >> 4, jn = n & 15;
    __shared__ __align__(16) bf16 Al[64 * 256];  // 32 KB rel rows (swizzled)
    __shared__ __align__(16) bf16 Bl[16 * 256];  // 8 KB Q2[.][n][.] (swizzled)
#pragma unroll
    for (int i = 0; i < 2; ++i) {
        const int slot = tid + i * 256;
        const int row = slot >> 5, g = slot & 31;
        Bl[row * 256 + ((g ^ (row & 7)) << 3)];  // addr compute only
        *reinterpret_cast<bf16x8*>(&Bl[row * 256 + ((g ^ (row & 7)) << 3)]) =
            ld8(Q2 + row * 65536 + n * 256 + g * 8);
    }
#pragma unroll
    for (int i = 0; i < 8; ++i) {
        const int slot = tid + i * 256;
        const int row = slot >> 5, g = slot & 31;
        const int m = m0 + row;
        const int ridx = ((m >> 4) - in_ + 15) * 31 + ((m & 15) - jn + 15);
        *reinterpret_cast<bf16x8*>(&Al[row * 256 + ((g ^ (row & 7)) << 3)]) =
            ld8(rpeb + ridx * 256 + g * 8);
    }
    __syncthreads();
    const int fr = l & 15, fk = (l >> 4) * 8;
    const int fx = (fr & 7) << 3;
    f32x4 acc = {};
#pragma unroll
    for (int ks = 0; ks < 8; ++ks) {
        const int eo = (ks * 32 + fk) ^ fx;
        const bf16x8 af = ld8(&Al[(w * 16 + fr) * 256 + eo]);
        const bf16x8 bg = ld8(&Bl[fr * 256 + eo]);
        acc = __builtin_amdgcn_mfma_f32_16x16x32_bf16(af, bg, acc, 0, 0, 0);
    }
    const int drow = (l >> 4) * 4, bh = l & 15;
#pragma unroll
    for (int r = 0; r < 4; ++r) {
        const int m = m0 + w * 16 + drow + r;
        S[n * 4096 + bh * 256 + m] = (bf16)acc[r];
    }
}

extern "C" void kernel_launch(void* const* d_in, const int* in_sizes, int n_in,
                              void* d_out, int out_size, void* d_ws, size_t ws_size,
                              hipStream_t stream) {
    const float* x = (const float*)d_in[0];
    const float* Wq = (const float*)d_in[1];
    const float* Wk = (const float*)d_in[2];
    const float* Wv = (const float*)d_in[3];
    const float* qg = (const float*)d_in[4];
    const float* qb = (const float*)d_in[5];
    const float* qm = (const float*)d_in[6];
    const float* qv = (const float*)d_in[7];
    const float* vg = (const float*)d_in[8];
    const float* vb = (const float*)d_in[9];
    const float* vm = (const float*)d_in[10];
    const float* vvar = (const float*)d_in[11];
    const float* rpe = (const float*)d_in[12];
    float* out = (float*)d_out;

    char* wsb = (char*)d_ws;
    bf16* xb = (bf16*)(wsb);
    bf16* WqT = (bf16*)(wsb + 0x200000u);
    bf16* WkT = (bf16*)(wsb + 0x400000u);
    bf16* WvT = (bf16*)(wsb + 0x480000u);
    bf16* rpeb = (bf16*)(wsb + 0x500000u);
    bf16* Q2 = (bf16*)(wsb + 0x580000u);
    bf16* ksm = (bf16*)(wsb + 0x780000u);
    bf16* vbn = (bf16*)(wsb + 0x800000u);
    bf16* LcT = (bf16*)(wsb + 0x880000u);
    bf16* S = (bf16*)(wsb + 0x900000u);
    float* kn = (float*)(wsb + 0x900000u);  // aliases S; consumed before S written

    const dim3 blk(256);
    prep<<<1853, blk, 0, stream>>>(x, Wq, Wk, Wv, rpe, xb, WqT, WkT, WvT, rpeb);
    proj_all<<<dim3(4, 16, 6), blk, 0, stream>>>(xb, WqT, WkT, WvT, qg, qb, qm, qv,
                                                 vg, vb, vm, vvar, Q2, kn, vbn);
    softmax_rows<<<256, blk, 0, stream>>>(kn, ksm);
    gk<3><<<dim3(4, 4, 4), blk, 0, stream>>>(vbn, ksm, LcT, nullptr, nullptr);
    s_gemm<<<dim3(4, 256), blk, 0, stream>>>(rpeb, Q2, S);
    gk<4><<<dim3(4, 4, 16), blk, 0, stream>>>(Q2, LcT, out, S, vbn);
}